// Round 4
// baseline (187.632 us; speedup 1.0000x reference)
//
#include <hip/hip_runtime.h>

#define Bb 16
#define Tt 12
#define Nn 1024
#define FIN 32
#define FOUT 64
#define KC 3
#define KJ (KC * Nn)     // 3072 — GEMM K dimension (k,j)
#define NO (Tt * FOUT)   // 768  — GEMM N dimension (t,o)

#define BM 256
#define BN 192
#define BK 64
#define NKT (KJ / BK)    // 48 K-tiles

typedef __attribute__((ext_vector_type(8))) short short8;
typedef __attribute__((ext_vector_type(4))) float f32x4;

__device__ __forceinline__ unsigned short f2bf(float f) {
  union { float f; unsigned u; } v; v.f = f;
  unsigned r = v.u + 0x7FFFu + ((v.u >> 16) & 1u);  // RNE
  return (unsigned short)(r >> 16);
}

__device__ __forceinline__ void BAR() {
  __builtin_amdgcn_sched_barrier(0);
  __builtin_amdgcn_s_barrier();
  __builtin_amdgcn_sched_barrier(0);
}

// ---------------------------------------------------------------------------
// k12: fused k1 (build A, grid-strided, blocks [0,2048)) + k2 (build Y,
// blocks [2048,2432)). Roles split at block granularity.
// ---------------------------------------------------------------------------
__global__ __launch_bounds__(256) void k12_build(
    const float* __restrict__ x, const float* __restrict__ att,
    const float* __restrict__ cheb, const float* __restrict__ theta,
    unsigned short* __restrict__ Acat, unsigned short* __restrict__ Yw) {
  __shared__ float th[KC * FOUT * FIN];  // k2-role only
  const int tid = threadIdx.x;
  if (blockIdx.x < 2048) {
    // ---- k1 role: A[b][i][k*N+j] = bf16(cheb[k,i,j] * att[b,i,j]) ----
    for (int v = blockIdx.x; v < 16384; v += 2048) {
      const unsigned idx = v * 256u + tid;  // (b, i, j/4)
      const int j = (idx & 255u) << 2;
      const int i = (idx >> 8) & 1023u;
      const int b = idx >> 18;
      const float4 av = *(const float4*)(att + ((size_t)b * Nn + i) * Nn + j);
      const size_t obase = ((size_t)b * Nn + i) * KJ + j;
#pragma unroll
      for (int k = 0; k < KC; ++k) {
        const float4 cv = *(const float4*)(cheb + ((size_t)k * Nn + i) * Nn + j);
        ushort4 o;
        o.x = f2bf(av.x * cv.x); o.y = f2bf(av.y * cv.y);
        o.z = f2bf(av.z * cv.z); o.w = f2bf(av.w * cv.w);
        *(ushort4*)(Acat + obase + (size_t)k * Nn) = o;
      }
    }
    return;
  }
  // ---- k2 role: Y[b][t*64+o][k*N+j] = bf16( sum_f x[b,t,j,f]*Theta[k,f,o] )
  for (int s = tid; s < KC * FOUT * FIN; s += 256) {
    const int k = s >> 11, rem = s & 2047, o = rem >> 5, f = rem & 31;
    th[s] = theta[(k * FIN + f) * FOUT + o];
  }
  __syncthreads();
  const int blk = blockIdx.x - 2048;
  const int half = blk & 1, bt = blk >> 1;
  const int t = bt % Tt, b = bt / Tt;
  const int j0 = half * 512 + tid * 2;
  const float* xp = x + ((size_t)(b * Tt + t) * Nn + j0) * FIN;
  float x0[FIN], x1[FIN];
#pragma unroll
  for (int q = 0; q < FIN / 4; ++q) {
    float4 v = *(const float4*)(xp + 4 * q);
    x0[4 * q] = v.x; x0[4 * q + 1] = v.y; x0[4 * q + 2] = v.z; x0[4 * q + 3] = v.w;
    float4 u = *(const float4*)(xp + FIN + 4 * q);
    x1[4 * q] = u.x; x1[4 * q + 1] = u.y; x1[4 * q + 2] = u.z; x1[4 * q + 3] = u.w;
  }
  const size_t ybase = (size_t)(b * NO + t * FOUT) * KJ;
  for (int k = 0; k < KC; ++k) {
    for (int o = 0; o < FOUT; ++o) {
      const float* tp = &th[(k * FOUT + o) * FIN];
      float a0 = 0.f, a1 = 0.f;
#pragma unroll
      for (int q = 0; q < FIN / 4; ++q) {
        float4 tv = *(const float4*)(tp + 4 * q);
        a0 = fmaf(x0[4 * q + 0], tv.x, a0); a1 = fmaf(x1[4 * q + 0], tv.x, a1);
        a0 = fmaf(x0[4 * q + 1], tv.y, a0); a1 = fmaf(x1[4 * q + 1], tv.y, a1);
        a0 = fmaf(x0[4 * q + 2], tv.z, a0); a1 = fmaf(x1[4 * q + 2], tv.z, a1);
        a0 = fmaf(x0[4 * q + 3], tv.w, a0); a1 = fmaf(x1[4 * q + 3], tv.w, a1);
      }
      const unsigned pack = (unsigned)f2bf(a0) | ((unsigned)f2bf(a1) << 16);
      *(unsigned*)(Yw + ybase + (size_t)o * KJ + k * Nn + j0) = pack;
    }
  }
}

// ---------------------------------------------------------------------------
// k3: per b: C[i,n] = sum_kj A[i,kj]·Y[n,kj], ReLU, scatter to out[b,t,i,o].
// 256×192 tile (exactly 256 blocks = 100% CU fill), 8 waves (2M×4N, wave
// 128×48), BK=64. 2 barriers/K-tile with reg-prefetch overlap:
//   reads(ks0) | MFMA q0 | reads(ks1) | MFMA q1 | lgkm(0)+BAR |
//   stage 7 units (τ+2) | MFMA q2,q3 (reg-only, DMA in flight) | vmcnt(7)+BAR
// Stage unit = 64 rows × 64 cols bf16 = 1 gload_lds instr/thread. 7 units/tile
// (A:4, B:3); end-vmcnt(7) keeps exactly this tile's stages → τ+1 resident.
// Safety: all dbuf-d ds_reads complete (lgkm 0) before mid-BAR; stages (→dbuf
// d, tile τ+2) issue only after; q2/q3 touch no LDS; cross-wave DMA visibility
// via end-BAR after each wave's vmcnt(7).
// ---------------------------------------------------------------------------
__global__ __launch_bounds__(512, 2) void k3_gemm(
    const unsigned short* __restrict__ A, const unsigned short* __restrict__ Yw,
    float* __restrict__ out) {
  __shared__ __align__(16) unsigned short lds[57344];  // A 2×32K B, B 2×24K B
  const int bid = blockIdx.x;
  const int logical = (bid & 7) * 32 + (bid >> 3);  // 256 blocks, bijective XCD chunking
  const int b  = logical >> 4;
  const int r  = logical & 15;
  const int it = r >> 2;
  const int nt = r & 3;
  const unsigned short* Ap = A  + ((size_t)b * Nn + it * BM) * KJ;
  const unsigned short* Bp = Yw + ((size_t)b * NO + nt * BN) * KJ;
  const int tid = threadIdx.x;
  const int w = tid >> 6, l = tid & 63;
  const int wm = w >> 2, wn = w & 3;     // 2 M-warps × 4 N-warps
  const int lrow = l & 15;
  const int c0 = l >> 4;                 // k-chunk base 0..3
  const int sx = lrow & 7;               // swizzle key (row & 7)

  f32x4 acc[8][3];
#pragma unroll
  for (int mi = 0; mi < 8; ++mi)
#pragma unroll
    for (int ni = 0; ni < 3; ++ni)
      acc[mi][ni] = (f32x4){0.f, 0.f, 0.f, 0.f};

  // Stage unit u of K-tile kt into dbuf d. u<4: A rows [u*64,u*64+64);
  // u>=4: B rows [(u-4)*64, ...). Linear LDS dest, inverse-swizzled source.
  auto STAGEU = [&](int d, int u, int kt) {
    const int flat = w * 64 + l;        // 0..511
    const int row  = flat >> 3;         // 0..63 within unit
    const int csrc = (flat & 7) ^ (row & 7);
    if (u < 4) {
      __builtin_amdgcn_global_load_lds(
          (const __attribute__((address_space(1))) void*)(Ap + (size_t)(u * 64 + row) * KJ + kt * BK + csrc * 8),
          (__attribute__((address_space(3))) void*)(lds + d * 16384 + u * 4096 + w * 512),
          16, 0, 0);
    } else {
      __builtin_amdgcn_global_load_lds(
          (const __attribute__((address_space(1))) void*)(Bp + (size_t)((u - 4) * 64 + row) * KJ + kt * BK + csrc * 8),
          (__attribute__((address_space(3))) void*)(lds + 32768 + d * 12288 + (u - 4) * 4096 + w * 512),
          16, 0, 0);
    }
  };

  auto LDA = [&](int d, int mi, int ks) -> short8 {
    const int row = wm * 128 + mi * 16 + lrow;      // 0..255
    const int ch  = (c0 | (ks << 2)) ^ sx;          // swizzled chunk
    return *(const short8*)&lds[d * 16384 + row * 64 + ch * 8];
  };
  auto LDB = [&](int d, int ni, int ks) -> short8 {
    const int row = wn * 48 + ni * 16 + lrow;       // 0..191
    const int ch  = (c0 | (ks << 2)) ^ sx;
    return *(const short8*)&lds[32768 + d * 12288 + row * 64 + ch * 8];
  };

  // ---- prologue: stage tiles 0 (→dbuf0) and 1 (→dbuf1); tile0 resident ----
#pragma unroll
  for (int kt = 0; kt < 2; ++kt)
#pragma unroll
    for (int u = 0; u < 7; ++u) STAGEU(kt, u, kt);
  asm volatile("s_waitcnt vmcnt(7)" ::: "memory");
  BAR();

  auto TILE = [&](int d, int tau) {
    const int t2 = (tau + 2 < NKT) ? tau + 2 : NKT - 1;  // clamped tail re-stage is safe
    short8 a0[4], a1[4], b0[3], b1[3], a2h[4], a2l[4];
#pragma unroll
    for (int mi = 0; mi < 4; ++mi) a0[mi] = LDA(d, mi, 0);
#pragma unroll
    for (int ni = 0; ni < 3; ++ni) b0[ni] = LDB(d, ni, 0);
#pragma unroll
    for (int mi = 0; mi < 4; ++mi) a1[mi] = LDA(d, mi + 4, 0);
#pragma unroll
    for (int ni = 0; ni < 3; ++ni) b1[ni] = LDB(d, ni, 1);
    // q0 (m0-3 × ks0) — overlaps drain of a1/b1 reads
    __builtin_amdgcn_s_setprio(1);
#pragma unroll
    for (int mi = 0; mi < 4; ++mi)
#pragma unroll
      for (int ni = 0; ni < 3; ++ni)
        acc[mi][ni] = __builtin_amdgcn_mfma_f32_16x16x32_bf16(a0[mi], b0[ni], acc[mi][ni], 0, 0, 0);
    __builtin_amdgcn_s_setprio(0);
    // prefetch ks1 A-fragments — drains under q1's MFMA
#pragma unroll
    for (int mi = 0; mi < 4; ++mi) a2h[mi] = LDA(d, mi + 4, 1);
#pragma unroll
    for (int mi = 0; mi < 4; ++mi) a2l[mi] = LDA(d, mi, 1);
    // q1 (m4-7 × ks0)
    __builtin_amdgcn_s_setprio(1);
#pragma unroll
    for (int mi = 0; mi < 4; ++mi)
#pragma unroll
      for (int ni = 0; ni < 3; ++ni)
        acc[mi + 4][ni] = __builtin_amdgcn_mfma_f32_16x16x32_bf16(a1[mi], b0[ni], acc[mi + 4][ni], 0, 0, 0);
    __builtin_amdgcn_s_setprio(0);
    // all dbuf-d reads complete before stages may overwrite (cross-wave WAR)
    asm volatile("s_waitcnt lgkmcnt(0)" ::: "memory");
    BAR();
    // stage tile τ+2 → dbuf d (7 units); DMA flies under q2/q3 MFMA
    __builtin_amdgcn_sched_barrier(0);
#pragma unroll
    for (int u = 0; u < 7; ++u) STAGEU(d, u, t2);
    __builtin_amdgcn_sched_barrier(0);
    // q2 (m4-7 × ks1), q3 (m0-3 × ks1) — register-only
    __builtin_amdgcn_s_setprio(1);
#pragma unroll
    for (int mi = 0; mi < 4; ++mi)
#pragma unroll
      for (int ni = 0; ni < 3; ++ni)
        acc[mi + 4][ni] = __builtin_amdgcn_mfma_f32_16x16x32_bf16(a2h[mi], b1[ni], acc[mi + 4][ni], 0, 0, 0);
#pragma unroll
    for (int mi = 0; mi < 4; ++mi)
#pragma unroll
      for (int ni = 0; ni < 3; ++ni)
        acc[mi][ni] = __builtin_amdgcn_mfma_f32_16x16x32_bf16(a2l[mi], b1[ni], acc[mi][ni], 0, 0, 0);
    __builtin_amdgcn_s_setprio(0);
    asm volatile("s_waitcnt vmcnt(7)" ::: "memory");  // τ+1 resident; never 0 (T4)
    BAR();
  };

  for (int tp = 0; tp < NKT / 2; ++tp) {
    TILE(0, 2 * tp);
    TILE(1, 2 * tp + 1);
  }
  asm volatile("s_waitcnt vmcnt(0)" ::: "memory");  // drain before endpgm

  const int rbase = it * BM + wm * 128;
  const int cbase = nt * BN + wn * 48;
#pragma unroll
  for (int mi = 0; mi < 8; ++mi) {
#pragma unroll
    for (int ni = 0; ni < 3; ++ni) {
      const int col = cbase + ni * 16 + lrow;   // n = t*64 + o
      const int t = col >> 6, o = col & 63;
      const int row0 = rbase + mi * 16 + (c0 << 2);
      float* op = out + ((size_t)(b * Tt + t) * Nn + row0) * FOUT + o;
      f32x4 v = acc[mi][ni];
#pragma unroll
      for (int q = 0; q < 4; ++q)
        op[(size_t)q * FOUT] = fmaxf(v[q], 0.f);
    }
  }
}

// ---------------------------------------------------------------------------
// fallback (ws too small): slow but correct, pure f32
// ---------------------------------------------------------------------------
__global__ __launch_bounds__(128) void k_fallback(
    const float* __restrict__ x, const float* __restrict__ att,
    const float* __restrict__ cheb, const float* __restrict__ theta,
    float* __restrict__ out) {
  const int blk = blockIdx.x;  // (b, t, i)
  const int i = blk & 1023;
  const int bt = blk >> 10;
  const int t = bt % Tt, b = bt / Tt;
  __shared__ float rhs[KC * FIN];
  const int tid = threadIdx.x;
  if (tid < KC * FIN) {
    const int k = tid >> 5, f = tid & 31;
    const float* ar = att + ((size_t)b * Nn + i) * Nn;
    const float* cr = cheb + ((size_t)k * Nn + i) * Nn;
    const float* xr = x + ((size_t)(b * Tt + t) * Nn) * FIN + f;
    float s = 0.f;
    for (int j = 0; j < Nn; ++j) s = fmaf(ar[j] * cr[j], xr[(size_t)j * FIN], s);
    rhs[tid] = s;
  }
  __syncthreads();
  if (tid < FOUT) {
    float a = 0.f;
#pragma unroll
    for (int kf = 0; kf < KC * FIN; ++kf) a = fmaf(rhs[kf], theta[kf * FOUT + tid], a);
    out[((size_t)(b * Tt + t) * Nn + i) * FOUT + tid] = fmaxf(a, 0.f);
  }
}

extern "C" void kernel_launch(void* const* d_in, const int* in_sizes, int n_in,
                              void* d_out, int out_size, void* d_ws, size_t ws_size,
                              hipStream_t stream) {
  const float* x     = (const float*)d_in[0];
  const float* att   = (const float*)d_in[1];
  const float* cheb  = (const float*)d_in[2];
  const float* theta = (const float*)d_in[3];
  float* out = (float*)d_out;

  const size_t needA = (size_t)Bb * Nn * KJ * sizeof(unsigned short);  // 96 MB
  const size_t needY = (size_t)Bb * NO * KJ * sizeof(unsigned short);  // 72 MB
  if (ws_size >= needA + needY) {
    unsigned short* Acat = (unsigned short*)d_ws;
    unsigned short* Yw   = (unsigned short*)((char*)d_ws + needA);
    hipLaunchKernelGGL(k12_build, dim3(2048 + Bb * Tt * 2), dim3(256), 0, stream,
                       x, att, cheb, theta, Acat, Yw);
    hipLaunchKernelGGL(k3_gemm, dim3(Bb * (Nn / BM) * (NO / BN)), dim3(512), 0, stream,
                       Acat, Yw, out);
  } else {
    hipLaunchKernelGGL(k_fallback, dim3(Bb * Tt * Nn), dim3(128), 0, stream,
                       x, att, cheb, theta, out);
  }
}

// Round 5
// 151.874 us; speedup vs baseline: 1.2354x; 1.2354x over previous
//
#include <hip/hip_runtime.h>

#define Bb 16
#define Tt 12
#define Nn 1024
#define FIN 32
#define FOUT 64
#define KC 3
#define KJ (KC * Nn)     // 3072 — GEMM K dimension (k,j)
#define NO (Tt * FOUT)   // 768  — GEMM N dimension (t,o)

#define BM 256
#define BN 192
#define BK 64
#define NKT (KJ / BK)    // 48 K-tiles

typedef __attribute__((ext_vector_type(8))) short short8;
typedef __attribute__((ext_vector_type(4))) float f32x4;

__device__ __forceinline__ unsigned short f2bf(float f) {
  union { float f; unsigned u; } v; v.f = f;
  unsigned r = v.u + 0x7FFFu + ((v.u >> 16) & 1u);  // RNE
  return (unsigned short)(r >> 16);
}

__device__ __forceinline__ void BAR() {
  __builtin_amdgcn_sched_barrier(0);
  __builtin_amdgcn_s_barrier();
  __builtin_amdgcn_sched_barrier(0);
}

// ---------------------------------------------------------------------------
// k1: A[b][i][k*N+j] = bf16(cheb[k,i,j] * att[b,i,j])
// thread -> (b, i, j/8): 16-B stores (was 8-B), 8192 blocks.
// ---------------------------------------------------------------------------
__global__ __launch_bounds__(256) void k1_build_A(
    const float* __restrict__ att, const float* __restrict__ cheb,
    unsigned short* __restrict__ Acat) {
  const unsigned idx = blockIdx.x * 256u + threadIdx.x;  // (b, i, j/8)
  const int j = (idx & 127u) << 3;
  const int i = (idx >> 7) & 1023u;
  const int b = idx >> 17;
  const float* ap = att + ((size_t)b * Nn + i) * Nn + j;
  const float4 a0 = *(const float4*)ap;
  const float4 a1 = *(const float4*)(ap + 4);
  const size_t obase = ((size_t)b * Nn + i) * KJ + j;
#pragma unroll
  for (int k = 0; k < KC; ++k) {
    const float* cp = cheb + ((size_t)k * Nn + i) * Nn + j;
    const float4 c0 = *(const float4*)cp;
    const float4 c1 = *(const float4*)(cp + 4);
    short8 o;
    o[0] = (short)f2bf(a0.x * c0.x); o[1] = (short)f2bf(a0.y * c0.y);
    o[2] = (short)f2bf(a0.z * c0.z); o[3] = (short)f2bf(a0.w * c0.w);
    o[4] = (short)f2bf(a1.x * c1.x); o[5] = (short)f2bf(a1.y * c1.y);
    o[6] = (short)f2bf(a1.z * c1.z); o[7] = (short)f2bf(a1.w * c1.w);
    *(short8*)(Acat + obase + (size_t)k * Nn) = o;
  }
}

// ---------------------------------------------------------------------------
// k2: Y[b][t*64+o][k*N+j] = bf16( sum_f x[b,t,j,f] * Theta[k,f,o] )
// MFMA version: K=32 == one mfma_f32_16x16x32_bf16. 768 blocks (b,t,jq),
// 4 waves; all 12 Theta B-frags held in registers; A-frag = 16 x-rows
// (2 KB contiguous); C gives each lane 4 consecutive j -> 8-B packed store.
// ---------------------------------------------------------------------------
__global__ __launch_bounds__(256) void k2_build_Y(
    const float* __restrict__ x, const float* __restrict__ theta,
    unsigned short* __restrict__ Yw) {
  __shared__ float th[KC * FIN * FOUT];  // [k][f][o] — same layout as input
  const int tid = threadIdx.x;
  for (int s = tid; s < KC * FIN * FOUT; s += 256) th[s] = theta[s];
  __syncthreads();

  const int l = tid & 63, w = tid >> 6;
  const int ocol = l & 15;
  const int fr0 = (l >> 4) * 8;          // 8 consecutive k-dim (=f) elems per lane

  // B-frags: lane holds Th[k][fr0+r][o0+ocol], r=0..7 — 12 frags in registers.
  short8 bfrag[KC * 4];
#pragma unroll
  for (int k = 0; k < KC; ++k)
#pragma unroll
    for (int ot = 0; ot < 4; ++ot) {
      short8 bf;
#pragma unroll
      for (int r = 0; r < 8; ++r)
        bf[r] = (short)f2bf(th[(k * FIN + fr0 + r) * FOUT + ot * 16 + ocol]);
      bfrag[k * 4 + ot] = bf;
    }

  const int blk = blockIdx.x;
  const int jq = blk & 3;                // j-quarter (256 j's)
  const int bt = blk >> 2;
  const int t = bt % Tt, b = bt / Tt;
  const size_t ybase = (size_t)(b * NO + t * FOUT) * KJ;
  const f32x4 zero = (f32x4){0.f, 0.f, 0.f, 0.f};

#pragma unroll
  for (int m = 0; m < 4; ++m) {
    const int j0 = jq * 256 + (w * 4 + m) * 16;
    // A-frag: lane holds x[j0 + (l&15)][fr0 .. fr0+8) — f32 -> bf16
    const float* xp = x + ((size_t)(b * Tt + t) * Nn + j0 + (l & 15)) * FIN + fr0;
    const float4 v0 = *(const float4*)xp;
    const float4 v1 = *(const float4*)(xp + 4);
    short8 af;
    af[0] = (short)f2bf(v0.x); af[1] = (short)f2bf(v0.y);
    af[2] = (short)f2bf(v0.z); af[3] = (short)f2bf(v0.w);
    af[4] = (short)f2bf(v1.x); af[5] = (short)f2bf(v1.y);
    af[6] = (short)f2bf(v1.z); af[7] = (short)f2bf(v1.w);

    f32x4 c[KC * 4];
#pragma unroll
    for (int ko = 0; ko < KC * 4; ++ko)
      c[ko] = __builtin_amdgcn_mfma_f32_16x16x32_bf16(af, bfrag[ko], zero, 0, 0, 0);
#pragma unroll
    for (int k = 0; k < KC; ++k)
#pragma unroll
      for (int ot = 0; ot < 4; ++ot) {
        const f32x4 cv = c[k * 4 + ot];
        const int o = ot * 16 + ocol;
        const int jrow = j0 + (l >> 4) * 4;    // 4 consecutive j (q=0..3)
        uint2 pk;
        pk.x = (unsigned)f2bf(cv[0]) | ((unsigned)f2bf(cv[1]) << 16);
        pk.y = (unsigned)f2bf(cv[2]) | ((unsigned)f2bf(cv[3]) << 16);
        *(uint2*)(Yw + ybase + (size_t)o * KJ + k * Nn + jrow) = pk;
      }
  }
}

// ---------------------------------------------------------------------------
// k3: per b: C[i,n] = sum_kj A[i,kj]·Y[n,kj], ReLU, scatter to out[b,t,i,o].
// 256×192 tile (exactly 256 blocks = 100% CU fill), 8 waves (2M×4N, wave
// 128×48), BK=64. 2 barriers/K-tile with reg-prefetch overlap. UNCHANGED (R4).
// ---------------------------------------------------------------------------
__global__ __launch_bounds__(512, 2) void k3_gemm(
    const unsigned short* __restrict__ A, const unsigned short* __restrict__ Yw,
    float* __restrict__ out) {
  __shared__ __align__(16) unsigned short lds[57344];  // A 2×32K B, B 2×24K B
  const int bid = blockIdx.x;
  const int logical = (bid & 7) * 32 + (bid >> 3);  // 256 blocks, bijective XCD chunking
  const int b  = logical >> 4;
  const int r  = logical & 15;
  const int it = r >> 2;
  const int nt = r & 3;
  const unsigned short* Ap = A  + ((size_t)b * Nn + it * BM) * KJ;
  const unsigned short* Bp = Yw + ((size_t)b * NO + nt * BN) * KJ;
  const int tid = threadIdx.x;
  const int w = tid >> 6, l = tid & 63;
  const int wm = w >> 2, wn = w & 3;     // 2 M-warps × 4 N-warps
  const int lrow = l & 15;
  const int c0 = l >> 4;                 // k-chunk base 0..3
  const int sx = lrow & 7;               // swizzle key (row & 7)

  f32x4 acc[8][3];
#pragma unroll
  for (int mi = 0; mi < 8; ++mi)
#pragma unroll
    for (int ni = 0; ni < 3; ++ni)
      acc[mi][ni] = (f32x4){0.f, 0.f, 0.f, 0.f};

  auto STAGEU = [&](int d, int u, int kt) {
    const int flat = w * 64 + l;        // 0..511
    const int row  = flat >> 3;         // 0..63 within unit
    const int csrc = (flat & 7) ^ (row & 7);
    if (u < 4) {
      __builtin_amdgcn_global_load_lds(
          (const __attribute__((address_space(1))) void*)(Ap + (size_t)(u * 64 + row) * KJ + kt * BK + csrc * 8),
          (__attribute__((address_space(3))) void*)(lds + d * 16384 + u * 4096 + w * 512),
          16, 0, 0);
    } else {
      __builtin_amdgcn_global_load_lds(
          (const __attribute__((address_space(1))) void*)(Bp + (size_t)((u - 4) * 64 + row) * KJ + kt * BK + csrc * 8),
          (__attribute__((address_space(3))) void*)(lds + 32768 + d * 12288 + (u - 4) * 4096 + w * 512),
          16, 0, 0);
    }
  };

  auto LDA = [&](int d, int mi, int ks) -> short8 {
    const int row = wm * 128 + mi * 16 + lrow;      // 0..255
    const int ch  = (c0 | (ks << 2)) ^ sx;          // swizzled chunk
    return *(const short8*)&lds[d * 16384 + row * 64 + ch * 8];
  };
  auto LDB = [&](int d, int ni, int ks) -> short8 {
    const int row = wn * 48 + ni * 16 + lrow;       // 0..191
    const int ch  = (c0 | (ks << 2)) ^ sx;
    return *(const short8*)&lds[32768 + d * 12288 + row * 64 + ch * 8];
  };

  // ---- prologue: stage tiles 0 (→dbuf0) and 1 (→dbuf1); tile0 resident ----
#pragma unroll
  for (int kt = 0; kt < 2; ++kt)
#pragma unroll
    for (int u = 0; u < 7; ++u) STAGEU(kt, u, kt);
  asm volatile("s_waitcnt vmcnt(7)" ::: "memory");
  BAR();

  auto TILE = [&](int d, int tau) {
    const int t2 = (tau + 2 < NKT) ? tau + 2 : NKT - 1;  // clamped tail re-stage is safe
    short8 a0[4], a1[4], b0[3], b1[3], a2h[4], a2l[4];
#pragma unroll
    for (int mi = 0; mi < 4; ++mi) a0[mi] = LDA(d, mi, 0);
#pragma unroll
    for (int ni = 0; ni < 3; ++ni) b0[ni] = LDB(d, ni, 0);
#pragma unroll
    for (int mi = 0; mi < 4; ++mi) a1[mi] = LDA(d, mi + 4, 0);
#pragma unroll
    for (int ni = 0; ni < 3; ++ni) b1[ni] = LDB(d, ni, 1);
    // q0 (m0-3 × ks0) — overlaps drain of a1/b1 reads
    __builtin_amdgcn_s_setprio(1);
#pragma unroll
    for (int mi = 0; mi < 4; ++mi)
#pragma unroll
      for (int ni = 0; ni < 3; ++ni)
        acc[mi][ni] = __builtin_amdgcn_mfma_f32_16x16x32_bf16(a0[mi], b0[ni], acc[mi][ni], 0, 0, 0);
    __builtin_amdgcn_s_setprio(0);
    // prefetch ks1 A-fragments — drains under q1's MFMA
#pragma unroll
    for (int mi = 0; mi < 4; ++mi) a2h[mi] = LDA(d, mi + 4, 1);
#pragma unroll
    for (int mi = 0; mi < 4; ++mi) a2l[mi] = LDA(d, mi, 1);
    // q1 (m4-7 × ks0)
    __builtin_amdgcn_s_setprio(1);
#pragma unroll
    for (int mi = 0; mi < 4; ++mi)
#pragma unroll
      for (int ni = 0; ni < 3; ++ni)
        acc[mi + 4][ni] = __builtin_amdgcn_mfma_f32_16x16x32_bf16(a1[mi], b0[ni], acc[mi + 4][ni], 0, 0, 0);
    __builtin_amdgcn_s_setprio(0);
    // all dbuf-d reads complete before stages may overwrite (cross-wave WAR)
    asm volatile("s_waitcnt lgkmcnt(0)" ::: "memory");
    BAR();
    // stage tile τ+2 → dbuf d (7 units); DMA flies under q2/q3 MFMA
    __builtin_amdgcn_sched_barrier(0);
#pragma unroll
    for (int u = 0; u < 7; ++u) STAGEU(d, u, t2);
    __builtin_amdgcn_sched_barrier(0);
    // q2 (m4-7 × ks1), q3 (m0-3 × ks1) — register-only
    __builtin_amdgcn_s_setprio(1);
#pragma unroll
    for (int mi = 0; mi < 4; ++mi)
#pragma unroll
      for (int ni = 0; ni < 3; ++ni)
        acc[mi + 4][ni] = __builtin_amdgcn_mfma_f32_16x16x32_bf16(a2h[mi], b1[ni], acc[mi + 4][ni], 0, 0, 0);
#pragma unroll
    for (int mi = 0; mi < 4; ++mi)
#pragma unroll
      for (int ni = 0; ni < 3; ++ni)
        acc[mi][ni] = __builtin_amdgcn_mfma_f32_16x16x32_bf16(a2l[mi], b1[ni], acc[mi][ni], 0, 0, 0);
    __builtin_amdgcn_s_setprio(0);
    asm volatile("s_waitcnt vmcnt(7)" ::: "memory");  // τ+1 resident; never 0 (T4)
    BAR();
  };

  for (int tp = 0; tp < NKT / 2; ++tp) {
    TILE(0, 2 * tp);
    TILE(1, 2 * tp + 1);
  }
  asm volatile("s_waitcnt vmcnt(0)" ::: "memory");  // drain before endpgm

  const int rbase = it * BM + wm * 128;
  const int cbase = nt * BN + wn * 48;
#pragma unroll
  for (int mi = 0; mi < 8; ++mi) {
#pragma unroll
    for (int ni = 0; ni < 3; ++ni) {
      const int col = cbase + ni * 16 + lrow;   // n = t*64 + o
      const int t = col >> 6, o = col & 63;
      const int row0 = rbase + mi * 16 + (c0 << 2);
      float* op = out + ((size_t)(b * Tt + t) * Nn + row0) * FOUT + o;
      f32x4 v = acc[mi][ni];
#pragma unroll
      for (int q = 0; q < 4; ++q)
        op[(size_t)q * FOUT] = fmaxf(v[q], 0.f);
    }
  }
}

// ---------------------------------------------------------------------------
// fallback (ws too small): slow but correct, pure f32
// ---------------------------------------------------------------------------
__global__ __launch_bounds__(128) void k_fallback(
    const float* __restrict__ x, const float* __restrict__ att,
    const float* __restrict__ cheb, const float* __restrict__ theta,
    float* __restrict__ out) {
  const int blk = blockIdx.x;  // (b, t, i)
  const int i = blk & 1023;
  const int bt = blk >> 10;
  const int t = bt % Tt, b = bt / Tt;
  __shared__ float rhs[KC * FIN];
  const int tid = threadIdx.x;
  if (tid < KC * FIN) {
    const int k = tid >> 5, f = tid & 31;
    const float* ar = att + ((size_t)b * Nn + i) * Nn;
    const float* cr = cheb + ((size_t)k * Nn + i) * Nn;
    const float* xr = x + ((size_t)(b * Tt + t) * Nn) * FIN + f;
    float s = 0.f;
    for (int j = 0; j < Nn; ++j) s = fmaf(ar[j] * cr[j], xr[(size_t)j * FIN], s);
    rhs[tid] = s;
  }
  __syncthreads();
  if (tid < FOUT) {
    float a = 0.f;
#pragma unroll
    for (int kf = 0; kf < KC * FIN; ++kf) a = fmaf(rhs[kf], theta[kf * FOUT + tid], a);
    out[((size_t)(b * Tt + t) * Nn + i) * FOUT + tid] = fmaxf(a, 0.f);
  }
}

extern "C" void kernel_launch(void* const* d_in, const int* in_sizes, int n_in,
                              void* d_out, int out_size, void* d_ws, size_t ws_size,
                              hipStream_t stream) {
  const float* x     = (const float*)d_in[0];
  const float* att   = (const float*)d_in[1];
  const float* cheb  = (const float*)d_in[2];
  const float* theta = (const float*)d_in[3];
  float* out = (float*)d_out;

  const size_t needA = (size_t)Bb * Nn * KJ * sizeof(unsigned short);  // 96 MB
  const size_t needY = (size_t)Bb * NO * KJ * sizeof(unsigned short);  // 72 MB
  if (ws_size >= needA + needY) {
    unsigned short* Acat = (unsigned short*)d_ws;
    unsigned short* Yw   = (unsigned short*)((char*)d_ws + needA);
    hipLaunchKernelGGL(k1_build_A, dim3(Bb * Nn * (Nn / 8) / 256), dim3(256), 0, stream,
                       att, cheb, Acat);
    hipLaunchKernelGGL(k2_build_Y, dim3(Bb * Tt * 4), dim3(256), 0, stream,
                       x, theta, Yw);
    hipLaunchKernelGGL(k3_gemm, dim3(Bb * (Nn / BM) * (NO / BN)), dim3(512), 0, stream,
                       Acat, Yw, out);
  } else {
    hipLaunchKernelGGL(k_fallback, dim3(Bb * Tt * Nn), dim3(128), 0, stream,
                       x, att, cheb, theta, out);
  }
}